// Round 1
// baseline (70.296 us; speedup 1.0000x reference)
//
#include <hip/hip_runtime.h>

#define NSEG 128
#define KC 64
#define BZ 64
#define PPS (BZ * BZ) // 4096 pixels per segment

// One block = 512 pixels of one segment (256 threads x 2 pixels).
// Thread t in chunk c handles p0 = c*512 + t and p1 = p0 + 256:
// same j (grid-y), grid-x differs -> B11*d1 term shared.
__global__ __launch_bounds__(256) void seg_gauss(const float* __restrict__ u,
                                                 const float* __restrict__ a,
                                                 const float* __restrict__ B,
                                                 float* __restrict__ out) {
    __shared__ float4 s_q[KC]; // {u0, u1, B00, B10}
    __shared__ float2 s_r[KC]; // {B11, a}

    const int t = threadIdx.x;
    const int blk = blockIdx.x;
    const int n = blk >> 3;     // 8 blocks per segment
    const int chunk = blk & 7;

    if (t < KC) {
        const float2 uk = ((const float2*)u)[n * KC + t];
        const float4 Bk = ((const float4*)B)[n * KC + t]; // {B00,B01,B10,B11}
        s_q[t] = make_float4(uk.x, uk.y, Bk.x, Bk.z);
        s_r[t] = make_float2(Bk.w, a[n * KC + t]);
    }
    __syncthreads();

    const int p0 = chunk * 512 + t;
    const int p1 = p0 + 256;
    const int i0 = p0 >> 6;
    const int i1 = p1 >> 6;
    const int j  = p0 & 63;
    const float inv64 = 1.0f / 64.0f;
    const float gx0 = (i0 + 0.5f) * inv64;
    const float gx1 = (i1 + 0.5f) * inv64;
    const float gy  = (j + 0.5f) * inv64;

    float w0[KC], w1[KC];
    float ks0 = 0.0f, ks1 = 0.0f;

#pragma unroll
    for (int k = 0; k < KC; ++k) {
        const float4 q = s_q[k];
        const float2 r = s_r[k];
        const float d1  = gy - q.y;
        const float t1  = r.x * d1;            // B11 * d1 (shared)
        const float d0a = gx0 - q.x;
        const float d0b = gx1 - q.x;
        const float v0a = q.z * d0a;           // B00 * d0
        const float v0b = q.z * d0b;
        const float v1a = fmaf(q.w, d0a, t1);  // B10*d0 + B11*d1
        const float v1b = fmaf(q.w, d0b, t1);
        const float sa = fmaf(v0a, v0a, v1a * v1a);
        const float sb = fmaf(v0b, v0b, v1b * v1b);
        const float ea = __expf(-0.5f * sa);
        const float eb = __expf(-0.5f * sb);
        ks0 += ea;
        ks1 += eb;
        w0[k] = r.y * ea;  // a_k * kern_k
        w1[k] = r.y * eb;
    }

    const float inv0 = 1.0f / fmaxf(ks0, 1e-7f);
    const float inv1 = 1.0f / fmaxf(ks1, 1e-7f);
    float z0 = 0.0f, z1 = 0.0f;
#pragma unroll
    for (int k = 0; k < KC; ++k) {
        z0 += fminf(w0[k] * inv0, 1.0f);
        z1 += fminf(w1[k] * inv1, 1.0f);
    }

    const size_t base = (size_t)n * PPS;
    out[base + p0] = z0;
    out[base + p1] = z1;
}

extern "C" void kernel_launch(void* const* d_in, const int* in_sizes, int n_in,
                              void* d_out, int out_size, void* d_ws, size_t ws_size,
                              hipStream_t stream) {
    const float* u = (const float*)d_in[0];
    const float* a = (const float*)d_in[1];
    const float* B = (const float*)d_in[2];
    float* out = (float*)d_out;

    dim3 grid(NSEG * 8); // 1024 blocks, 512 px each
    seg_gauss<<<grid, 256, 0, stream>>>(u, a, B, out);
}

// Round 2
// 66.471 us; speedup vs baseline: 1.0575x; 1.0575x over previous
//
#include <hip/hip_runtime.h>

#define NSEG 128
#define KC 64
#define BZ 64
#define PPS (BZ * BZ) // 4096 pixels per segment

// One block = 1024 pixels of one segment (256 threads x 4 pixels).
// Thread t handles p0, p0+256, p0+512, p0+768: same j (grid-y), so the
// B11*d1 term is shared across all 4 pixels.
//
// Clip identity: a_k in [0,1) and e_k/S <= 1  =>  min(a_k*e_k/S, 1) = a_k*e_k/S,
// so z = (sum a_k e_k) / max(sum e_k, eps). Single pass, no per-k state.
__global__ __launch_bounds__(256) void seg_gauss(const float* __restrict__ u,
                                                 const float* __restrict__ a,
                                                 const float* __restrict__ B,
                                                 float* __restrict__ out) {
    __shared__ float4 s_q[KC]; // {u0, u1, c*B00, c*B10}   c = sqrt(0.5)
    __shared__ float2 s_r[KC]; // {c*B11, a}

    const int t = threadIdx.x;
    const int blk = blockIdx.x;
    const int n = blk >> 2;     // 4 blocks per segment
    const int chunk = blk & 3;

    if (t < KC) {
        const float c = 0.70710678f; // sqrt(0.5): folds the -0.5 into ||Bd||^2
        const float2 uk = ((const float2*)u)[n * KC + t];
        const float4 Bk = ((const float4*)B)[n * KC + t]; // {B00,B01,B10,B11}
        s_q[t] = make_float4(uk.x, uk.y, c * Bk.x, c * Bk.z);
        s_r[t] = make_float2(c * Bk.w, a[n * KC + t]);
    }
    __syncthreads();

    const int p0 = chunk * 1024 + t;
    const int j  = p0 & 63;
    const float inv64 = 1.0f / 64.0f;
    const float gy = (j + 0.5f) * inv64;

    float gx[4];
#pragma unroll
    for (int q = 0; q < 4; ++q)
        gx[q] = (((p0 + q * 256) >> 6) + 0.5f) * inv64;

    float ks[4]  = {0.f, 0.f, 0.f, 0.f};
    float num[4] = {0.f, 0.f, 0.f, 0.f};

#pragma unroll
    for (int k = 0; k < KC; ++k) {
        const float4 qk = s_q[k];
        const float2 rk = s_r[k];
        const float d1 = gy - qk.y;
        const float t1 = rk.x * d1;            // c*B11*d1 (shared by 4 px)
#pragma unroll
        for (int q = 0; q < 4; ++q) {
            const float d0 = gx[q] - qk.x;
            const float v0 = qk.z * d0;                   // c*B00*d0
            const float v1 = fmaf(qk.w, d0, t1);          // c*(B10*d0+B11*d1)
            const float s  = fmaf(v0, v0, v1 * v1);       // 0.5*||Bd||^2
            const float e  = __expf(-s);                  // negate folds into mul
            ks[q]  += e;
            num[q]  = fmaf(rk.y, e, num[q]);
        }
    }

    const size_t base = (size_t)n * PPS;
#pragma unroll
    for (int q = 0; q < 4; ++q)
        out[base + p0 + q * 256] = num[q] / fmaxf(ks[q], 1e-7f);
}

extern "C" void kernel_launch(void* const* d_in, const int* in_sizes, int n_in,
                              void* d_out, int out_size, void* d_ws, size_t ws_size,
                              hipStream_t stream) {
    const float* u = (const float*)d_in[0];
    const float* a = (const float*)d_in[1];
    const float* B = (const float*)d_in[2];
    float* out = (float*)d_out;

    dim3 grid(NSEG * 4); // 512 blocks, 1024 px each
    seg_gauss<<<grid, 256, 0, stream>>>(u, a, B, out);
}

// Round 3
// 64.597 us; speedup vs baseline: 1.0882x; 1.0290x over previous
//
#include <hip/hip_runtime.h>

#define NSEG 128
#define KC 64
#define BZ 64
#define PPS (BZ * BZ) // 4096 pixels per segment

// z[n,p] = (sum_k a_k e_k) / max(sum_k e_k, eps),  e_k = exp(-0.5||tril(B_k) d||^2)
// (clip never binds: a in [0,1), e_k/sum <= 1; verified R1->R2, absmax unchanged)
//
// For fixed (k, gy): s2 = -log2e*0.5||Bd||^2 is quadratic in gx:
//   s2 = A*gx^2 + Bc*gx + Cc,  e_k = exp2(s2)   (v_exp_f32 is native 2^x)
// Staged per k (8 floats, 2x b128 broadcast reads):
//   P   = -0.5*L*(B00^2+B10^2)      (A)
//   Q   = -L*B10*B11
//   m   = -2*P*u0
//   R   = -0.5*L*B11^2
//   nQu = -Q*u0
//   Pu2 = P*u0^2
// Per thread per k (gy fixed): d1 = gy-u1; Bc = fma(Q,d1,m);
//   Cc = fma(d1, fma(R,d1,nQu), Pu2)
// Per pixel: s2 = fma(fma(A,gx,Bc),gx,Cc); e = exp2(s2); ks+=e; num=fma(a,e,num)
//   -> 4 VALU + 1 trans per pixel.
__global__ __launch_bounds__(256) void seg_gauss(const float* __restrict__ u,
                                                 const float* __restrict__ a,
                                                 const float* __restrict__ B,
                                                 float* __restrict__ out) {
    __shared__ float4 s_c1[KC]; // {u1, Q, m, R}
    __shared__ float4 s_c2[KC]; // {nQu, Pu2, A(=P), a}

    const int t = threadIdx.x;
    const int blk = blockIdx.x;
    const int n = blk >> 2;     // 4 blocks per segment
    const int chunk = blk & 3;

    if (t < KC) {
        const float cL = -0.72134752f; // -0.5*log2(e)
        const float2 uk = ((const float2*)u)[n * KC + t];
        const float4 Bk = ((const float4*)B)[n * KC + t]; // {B00,B01,B10,B11}
        const float P  = cL * fmaf(Bk.x, Bk.x, Bk.z * Bk.z); // -0.5L(B00^2+B10^2)
        const float Q  = 2.0f * cL * Bk.z * Bk.w;            // -L*B10*B11
        const float R  = cL * Bk.w * Bk.w;                   // -0.5L*B11^2
        const float m  = -2.0f * P * uk.x;
        const float nQu = -Q * uk.x;
        const float Pu2 = P * uk.x * uk.x;
        s_c1[t] = make_float4(uk.y, Q, m, R);
        s_c2[t] = make_float4(nQu, Pu2, P, a[n * KC + t]);
    }
    __syncthreads();

    const int p0 = chunk * 1024 + t;
    const int j  = p0 & 63;
    const float inv64 = 1.0f / 64.0f;
    const float gy = (j + 0.5f) * inv64;

    float gx[4];
#pragma unroll
    for (int q = 0; q < 4; ++q)
        gx[q] = (((p0 + q * 256) >> 6) + 0.5f) * inv64;

    float ks[4]  = {0.f, 0.f, 0.f, 0.f};
    float num[4] = {0.f, 0.f, 0.f, 0.f};

#pragma unroll
    for (int k = 0; k < KC; ++k) {
        const float4 c1 = s_c1[k];
        const float4 c2 = s_c2[k];
        const float d1 = gy - c1.x;                       // gy - u1
        const float Bc = fmaf(c1.y, d1, c1.z);            // Q*d1 + m
        const float Cc = fmaf(d1, fmaf(c1.w, d1, c2.x), c2.y); // d1*(R*d1+nQu)+Pu2
#pragma unroll
        for (int q = 0; q < 4; ++q) {
            const float s2 = fmaf(fmaf(c2.z, gx[q], Bc), gx[q], Cc);
            const float e  = __builtin_amdgcn_exp2f(s2);
            ks[q] += e;
            num[q] = fmaf(c2.w, e, num[q]);
        }
    }

    const size_t base = (size_t)n * PPS;
#pragma unroll
    for (int q = 0; q < 4; ++q)
        out[base + p0 + q * 256] = num[q] / fmaxf(ks[q], 1e-7f);
}

extern "C" void kernel_launch(void* const* d_in, const int* in_sizes, int n_in,
                              void* d_out, int out_size, void* d_ws, size_t ws_size,
                              hipStream_t stream) {
    const float* u = (const float*)d_in[0];
    const float* a = (const float*)d_in[1];
    const float* B = (const float*)d_in[2];
    float* out = (float*)d_out;

    dim3 grid(NSEG * 4); // 512 blocks, 1024 px each
    seg_gauss<<<grid, 256, 0, stream>>>(u, a, B, out);
}